// Round 1
// baseline (30.075 us; speedup 1.0000x reference)
//
#include <hip/hip_runtime.h>
#include <math.h>

namespace {
constexpr int L = 7, S = 200, SE = 240, D = 32, B = 512;

// C[l,s,d] = sum_e sigmoid(gain[l,s,e,0]) * (blk[l,s,e,0]!=0) * vec[l,s,e,d]
// One block per (l,s). 256 threads: tid = (eg<<3)|d4, eg in [0,32), d4 in [0,8) float4 column.
__global__ __launch_bounds__(256) void compose_kernel(
    const float* __restrict__ vec,     // [L,S,SE,D]
    const float* __restrict__ gain,    // [L,S,SE,2]
    const int* __restrict__ blk,       // [L,S,SE,2]
    float* __restrict__ C)             // [L*S, D]
{
  const int ls = blockIdx.x;
  const int tid = threadIdx.x;
  __shared__ float w[SE];
  if (tid < SE) {
    const int gi = (ls * SE + tid) * 2;
    const float g = gain[gi];
    const int b = blk[gi];
    const float sig = 1.0f / (1.0f + expf(-g));
    w[tid] = (b != 0) ? sig : 0.0f;
  }
  __syncthreads();
  const int d4 = tid & 7;
  const int eg = tid >> 3;
  const float4* v4 = reinterpret_cast<const float4*>(vec) + (size_t)ls * SE * 8;
  float4 acc = make_float4(0.f, 0.f, 0.f, 0.f);
  // wave = 8 consecutive e-rows x 8 float4 cols -> fully coalesced 1 KiB per step
  for (int e = eg; e < SE; e += 32) {
    const float we = w[e];
    const float4 v = v4[e * 8 + d4];
    acc.x += we * v.x; acc.y += we * v.y; acc.z += we * v.z; acc.w += we * v.w;
  }
  __shared__ float4 red[32][8];
  red[eg][d4] = acc;
  __syncthreads();
#pragma unroll
  for (int off = 16; off > 0; off >>= 1) {
    if (eg < off) {
      float4 a = red[eg][d4];
      const float4 o = red[eg + off][d4];
      a.x += o.x; a.y += o.y; a.z += o.z; a.w += o.w;
      red[eg][d4] = a;
    }
    __syncthreads();
  }
  if (tid < 8) {
    reinterpret_cast<float4*>(C + ls * D)[tid] = red[0][tid];
  }
}

// One block (1 wave, 64 lanes) per (l,b) token:
//  - 200 dot products vs cluster centroids (L2-hot, 25.6 KB/layer)
//  - exact top-3 (jax tie-break: desc value, lower index first) via butterfly merge
//  - softmax over the 3 vals, then out = sum_k p_k * C[l, idx_k, :]
__global__ __launch_bounds__(64) void route_kernel(
    const float* __restrict__ x,     // [L,B,D]
    const float* __restrict__ vc,    // [L,S,D]
    const float* __restrict__ C,     // [L*S, D]
    float* __restrict__ out)         // [L,B,D]
{
  const int lb = blockIdx.x;
  const int l = lb >> 9;  // B = 512
  const int lane = threadIdx.x;
  __shared__ float xs[D];
  if (lane < D) xs[lane] = x[lb * D + lane];
  __syncthreads();

  float v0 = -INFINITY, v1 = -INFINITY, v2 = -INFINITY;
  int i0 = 0x7fffffff, i1 = 0x7fffffff, i2 = 0x7fffffff;
  const float* vcl = vc + l * S * D;
  for (int s = lane; s < S; s += 64) {  // every lane gets >= 3 clusters (200/64)
    const float4* row = reinterpret_cast<const float4*>(vcl + s * D);
    float dot = 0.f;
#pragma unroll
    for (int q = 0; q < 8; ++q) {
      const float4 r = row[q];
      const float4 xx = reinterpret_cast<const float4*>(xs)[q];
      dot += r.x * xx.x; dot += r.y * xx.y; dot += r.z * xx.z; dot += r.w * xx.w;
    }
    // strict > keeps the earlier (smaller) index on ties; s increases per thread
    if (dot > v0) { v2 = v1; i2 = i1; v1 = v0; i1 = i0; v0 = dot; i0 = s; }
    else if (dot > v1) { v2 = v1; i2 = i1; v1 = dot; i1 = s; }
    else if (dot > v2) { v2 = dot; i2 = s; }
  }

  // butterfly merge: all 64 lanes converge to the global sorted top-3
#pragma unroll
  for (int m = 1; m < 64; m <<= 1) {
    const float u0 = __shfl_xor(v0, m);
    const float u1 = __shfl_xor(v1, m);
    const float u2 = __shfl_xor(v2, m);
    const int j0 = __shfl_xor(i0, m);
    const int j1 = __shfl_xor(i1, m);
    const int j2 = __shfl_xor(i2, m);
#pragma unroll
    for (int t = 0; t < 3; ++t) {
      const float u = (t == 0) ? u0 : (t == 1) ? u1 : u2;
      const int j = (t == 0) ? j0 : (t == 1) ? j1 : j2;
      const bool b0 = (u > v0) || (u == v0 && j < i0);
      const bool b1 = (u > v1) || (u == v1 && j < i1);
      const bool b2 = (u > v2) || (u == v2 && j < i2);
      if (b0) { v2 = v1; i2 = i1; v1 = v0; i1 = i0; v0 = u; i0 = j; }
      else if (b1) { v2 = v1; i2 = i1; v1 = u; i1 = j; }
      else if (b2) { v2 = u; i2 = j; }
    }
  }

  // softmax over (v0,v1,v2); v0 is the max
  const float e0 = expf(v0 - v0);
  const float e1 = expf(v1 - v0);
  const float e2 = expf(v2 - v0);
  const float inv = 1.f / (e0 + e1 + e2);
  const float p0 = e0 * inv, p1 = e1 * inv, p2 = e2 * inv;

  if (lane < D) {
    const float c0 = C[(l * S + i0) * D + lane];
    const float c1 = C[(l * S + i1) * D + lane];
    const float c2 = C[(l * S + i2) * D + lane];
    out[lb * D + lane] = p0 * c0 + p1 * c1 + p2 * c2;
  }
}

}  // namespace

extern "C" void kernel_launch(void* const* d_in, const int* in_sizes, int n_in,
                              void* d_out, int out_size, void* d_ws, size_t ws_size,
                              hipStream_t stream) {
  const float* x = (const float*)d_in[0];      // [L,B,D]
  const float* vc = (const float*)d_in[1];     // [L,S,D]
  const float* vec = (const float*)d_in[2];    // [L,S,SE,D]
  const float* gain = (const float*)d_in[3];   // [L,S,SE,2]
  const int* blk = (const int*)d_in[4];        // [L,S,SE,2]
  float* out = (float*)d_out;                  // [L,B,D]
  float* C = (float*)d_ws;                     // L*S*D floats = 179,200 B scratch

  compose_kernel<<<L * S, 256, 0, stream>>>(vec, gain, blk, C);
  route_kernel<<<L * B, 64, 0, stream>>>(x, vc, C, out);
}

// Round 2
// 29.244 us; speedup vs baseline: 1.0284x; 1.0284x over previous
//
#include <hip/hip_runtime.h>
#include <math.h>

namespace {
constexpr int L = 7, S = 200, SE = 240, D = 32, B = 512;
constexpr int NTOK = L * B;                 // 3584
constexpr int NCOMPOSE = (L * S) / 4;       // 350 blocks, 4 waves each, wave-per-(l,s)
constexpr int NROUTE = NTOK / 4;            // 896 blocks, 4 waves each, wave-per-token

// Fused: blocks [0,NCOMPOSE) compose C[l,s,:]; blocks [NCOMPOSE,..) do router phase 1.
__global__ __launch_bounds__(256) void fused1_kernel(
    const float* __restrict__ x,     // [L,B,D]
    const float* __restrict__ vc,    // [L,S,D]
    const float* __restrict__ vec,   // [L,S,SE,D]
    const float* __restrict__ gain,  // [L,S,SE,2]
    const int* __restrict__ blk,     // [L,S,SE,2]
    float* __restrict__ C,           // [L*S, D]
    int4* __restrict__ tk_idx,       // [NTOK]
    float4* __restrict__ tk_p)       // [NTOK]
{
  const int wave = threadIdx.x >> 6;
  const int lane = threadIdx.x & 63;

  if (blockIdx.x < NCOMPOSE) {
    // ---- compose: one wave per (l,s) ----
    __shared__ float wl[4][SE];
    const int ls = blockIdx.x * 4 + wave;
    for (int e = lane; e < SE; e += 64) {
      const int gi = (ls * SE + e) * 2;
      const float g = gain[gi];
      const int b = blk[gi];
      wl[wave][e] = (b != 0) ? 1.0f / (1.0f + expf(-g)) : 0.0f;
    }
    __syncthreads();
    const int d4 = lane & 7;   // float4 column
    const int eg = lane >> 3;  // e-row group [0,8)
    const float4* v4 = reinterpret_cast<const float4*>(vec) + (size_t)ls * SE * 8;
    float4 acc = make_float4(0.f, 0.f, 0.f, 0.f);
    for (int e = eg; e < SE; e += 8) {  // 30 iters; wave reads 8 rows x 128B contiguous
      const float we = wl[wave][e];
      const float4 v = v4[e * 8 + d4];
      acc.x += we * v.x; acc.y += we * v.y; acc.z += we * v.z; acc.w += we * v.w;
    }
#pragma unroll
    for (int m = 8; m < 64; m <<= 1) {  // reduce over eg bits (lane bits 3..5)
      acc.x += __shfl_xor(acc.x, m);
      acc.y += __shfl_xor(acc.y, m);
      acc.z += __shfl_xor(acc.z, m);
      acc.w += __shfl_xor(acc.w, m);
    }
    if (eg == 0) reinterpret_cast<float4*>(C + ls * D)[d4] = acc;
  } else {
    // ---- router phase 1: one wave per token ----
    __shared__ float xs[4][D];
    const int lb = (blockIdx.x - NCOMPOSE) * 4 + wave;
    const int l = lb >> 9;  // B = 512
    if (lane < D) xs[wave][lane] = x[lb * D + lane];
    __syncthreads();

    float v0 = -INFINITY, v1 = -INFINITY, v2 = -INFINITY;
    int i0 = 0x7fffffff, i1 = 0x7fffffff, i2 = 0x7fffffff;
    const float* vcl = vc + l * S * D;
    for (int s = lane; s < S; s += 64) {
      const float4* row = reinterpret_cast<const float4*>(vcl + s * D);
      float dot = 0.f;
#pragma unroll
      for (int q = 0; q < 8; ++q) {
        const float4 r = row[q];
        const float4 xx = reinterpret_cast<const float4*>(xs[wave])[q];
        dot += r.x * xx.x; dot += r.y * xx.y; dot += r.z * xx.z; dot += r.w * xx.w;
      }
      // strict > keeps earlier (smaller) index on ties; s increases per lane
      if (dot > v0) { v2 = v1; i2 = i1; v1 = v0; i1 = i0; v0 = dot; i0 = s; }
      else if (dot > v1) { v2 = v1; i2 = i1; v1 = dot; i1 = s; }
      else if (dot > v2) { v2 = dot; i2 = s; }
    }
#pragma unroll
    for (int m = 1; m < 64; m <<= 1) {  // butterfly merge of sorted-3 lists
      const float u0 = __shfl_xor(v0, m);
      const float u1 = __shfl_xor(v1, m);
      const float u2 = __shfl_xor(v2, m);
      const int j0 = __shfl_xor(i0, m);
      const int j1 = __shfl_xor(i1, m);
      const int j2 = __shfl_xor(i2, m);
#pragma unroll
      for (int t = 0; t < 3; ++t) {
        const float u = (t == 0) ? u0 : (t == 1) ? u1 : u2;
        const int j = (t == 0) ? j0 : (t == 1) ? j1 : j2;
        const bool b0 = (u > v0) || (u == v0 && j < i0);
        const bool b1 = (u > v1) || (u == v1 && j < i1);
        const bool b2 = (u > v2) || (u == v2 && j < i2);
        if (b0) { v2 = v1; i2 = i1; v1 = v0; i1 = i0; v0 = u; i0 = j; }
        else if (b1) { v2 = v1; i2 = i1; v1 = u; i1 = j; }
        else if (b2) { v2 = u; i2 = j; }
      }
    }
    if (lane == 0) {
      const float e1 = expf(v1 - v0);
      const float e2 = expf(v2 - v0);
      const float inv = 1.f / (1.f + e1 + e2);
      tk_idx[lb] = make_int4(i0, i1, i2, 0);
      tk_p[lb] = make_float4(inv, e1 * inv, e2 * inv, 0.f);
    }
  }
}

// out[token,d] = sum_k p_k * C[l, idx_k, d] ; thread per (token,d)
__global__ __launch_bounds__(256) void gather_kernel(
    const float* __restrict__ C,        // [L*S, D]
    const int4* __restrict__ tk_idx,    // [NTOK]
    const float4* __restrict__ tk_p,    // [NTOK]
    float* __restrict__ out)            // [L,B,D]
{
  const int gid = blockIdx.x * 256 + threadIdx.x;
  const int token = gid >> 5;
  const int d = gid & 31;
  const int l = token >> 9;
  const int4 id = tk_idx[token];
  const float4 p = tk_p[token];
  const float* Cl = C + l * S * D;
  out[gid] = p.x * Cl[id.x * D + d] + p.y * Cl[id.y * D + d] + p.z * Cl[id.z * D + d];
}

}  // namespace

extern "C" void kernel_launch(void* const* d_in, const int* in_sizes, int n_in,
                              void* d_out, int out_size, void* d_ws, size_t ws_size,
                              hipStream_t stream) {
  const float* x = (const float*)d_in[0];      // [L,B,D]
  const float* vc = (const float*)d_in[1];     // [L,S,D]
  const float* vec = (const float*)d_in[2];    // [L,S,SE,D]
  const float* gain = (const float*)d_in[3];   // [L,S,SE,2]
  const int* blk = (const int*)d_in[4];        // [L,S,SE,2]
  float* out = (float*)d_out;                  // [L,B,D]

  char* ws = (char*)d_ws;
  float* C = (float*)ws;                              // 179,200 B
  int4* tk_idx = (int4*)(ws + 179200);                // 57,344 B (16B aligned)
  float4* tk_p = (float4*)(ws + 179200 + 57344);      // 57,344 B

  fused1_kernel<<<NCOMPOSE + NROUTE, 256, 0, stream>>>(x, vc, vec, gain, blk, C, tk_idx, tk_p);
  gather_kernel<<<NTOK * D / 256, 256, 0, stream>>>(C, tk_idx, tk_p, out);
}